// Round 1
// 1554.002 us; speedup vs baseline: 1.5300x; 1.5300x over previous
//
#include <hip/hip_runtime.h>
#include <cmath>

// Problem constants
#define B_  32
#define T_  128
#define H_  512
#define V_  32000
#define G3  1536   // 3*H

typedef unsigned short u16;
typedef unsigned int   u32;
typedef __attribute__((ext_vector_type(8))) short short8;
typedef __attribute__((ext_vector_type(4))) float f32x4;

__device__ __forceinline__ u16 f2bf(float x) {
  u32 u = __float_as_uint(x);
  u32 r = (u + 0x7FFFu + ((u >> 16) & 1u)) >> 16;   // RNE
  return (u16)r;
}

__device__ __forceinline__ void gl_lds16(const void* g, void* l) {
  __builtin_amdgcn_global_load_lds(
      (const __attribute__((address_space(1))) void*)g,
      (__attribute__((address_space(3))) void*)l, 16, 0, 0);
}

// ---------------- f32 -> bf16 conversion (n4 = n/4 float4 groups) --------
__global__ void cvt_bf16(const float* __restrict__ s, u16* __restrict__ d, int n4) {
  int i = blockIdx.x * blockDim.x + threadIdx.x;
  int stride = gridDim.x * blockDim.x;
  for (; i < n4; i += stride) {
    float4 v = ((const float4*)s)[i];
    ushort4 o;
    o.x = f2bf(v.x); o.y = f2bf(v.y); o.z = f2bf(v.z); o.w = f2bf(v.w);
    ((ushort4*)d)[i] = o;
  }
}

// ------------- gather teacher-forced tokens -> x_bf[(t*B+b)][H] ----------
// grid 1024 x 256 exactly covers 4096 rows * 64 threads/row
__global__ void gather_x(const u16* __restrict__ emb_bf, const int* __restrict__ target,
                         u16* __restrict__ x_bf, u32* __restrict__ bar) {
  int idx = blockIdx.x * blockDim.x + threadIdx.x;
  if (idx < 512) bar[idx] = 0u;            // init 32 x 64B-padded GRU flags (ws re-poisoned each call)
  int row = idx >> 6;                      // m = t*B + b
  int c = (idx & 63) << 3;                 // 8 u16 (16 B) per thread
  int t = row >> 5, b = row & 31;
  int tok = (t == 0) ? 1 : target[b * T_ + t - 1];   // START token = 1
  *(uint4*)(x_bf + (size_t)row * H_ + c) = *(const uint4*)(emb_bf + (size_t)tok * H_ + c);
}

// ---------------- m97-style bf16 MFMA GEMM: C = A * Bt^T + bias ----------
// A [M][K] bf16 row-major, Bt [N][K] bf16 row-major, C fp32.
// remap=0: C[m*N+n].  remap=1: m = t*B+b  ->  C[(b*T + t)*N + n]  (logits layout)
__global__ __launch_bounds__(256) void gemm_bt(
    const u16* __restrict__ A, const u16* __restrict__ Bt,
    const float* __restrict__ bias, float* __restrict__ C,
    int M, int N, int K, int remap)
{
  __shared__ u16 lA[128 * 64];
  __shared__ u16 lB[128 * 64];
  const int tid  = threadIdx.x;
  const int wave = tid >> 6, lane = tid & 63;
  const int q = lane >> 4, l16 = lane & 15;
  const int tileN = blockIdx.x * 128, tileM = blockIdx.y * 128;
  const int wm = wave >> 1, wn = wave & 1;

  const f32x4 zero = {0.f, 0.f, 0.f, 0.f};
  f32x4 acc[4][4];
#pragma unroll
  for (int i = 0; i < 4; ++i)
#pragma unroll
    for (int j = 0; j < 4; ++j) acc[i][j] = zero;

  const int r8 = lane >> 3;          // row within 8-row staging stripe
  const int c8 = (lane & 7) << 3;    // u16 col offset (16 B granules)
  const int kIters = K >> 6;

  for (int kt = 0; kt < kIters; ++kt) {
    const int k0 = kt << 6;
#pragma unroll
    for (int j = 0; j < 4; ++j) {
      int r0 = wave * 32 + j * 8;    // wave-uniform
      gl_lds16(A  + (size_t)(tileM + r0 + r8) * K + k0 + c8, lA + r0 * 64);
      gl_lds16(Bt + (size_t)(tileN + r0 + r8) * K + k0 + c8, lB + r0 * 64);
    }
    __syncthreads();                 // drains vmcnt then barrier
#pragma unroll
    for (int ks = 0; ks < 2; ++ks) {
      const int kk = ks * 32 + q * 8;
      short8 af[4], bfv[4];
#pragma unroll
      for (int mi = 0; mi < 4; ++mi)
        af[mi] = *(const short8*)(lA + (wm * 64 + mi * 16 + l16) * 64 + kk);
#pragma unroll
      for (int ni = 0; ni < 4; ++ni)
        bfv[ni] = *(const short8*)(lB + (wn * 64 + ni * 16 + l16) * 64 + kk);
#pragma unroll
      for (int mi = 0; mi < 4; ++mi)
#pragma unroll
        for (int ni = 0; ni < 4; ++ni)
          acc[mi][ni] = __builtin_amdgcn_mfma_f32_16x16x32_bf16(af[mi], bfv[ni], acc[mi][ni], 0, 0, 0);
    }
    __syncthreads();
  }

#pragma unroll
  for (int mi = 0; mi < 4; ++mi) {
#pragma unroll
    for (int ni = 0; ni < 4; ++ni) {
      int n = tileN + wn * 64 + ni * 16 + l16;
      float bs = bias[n];
#pragma unroll
      for (int r = 0; r < 4; ++r) {
        int m = tileM + wm * 64 + mi * 16 + q * 4 + r;   // C/D: row=(lane>>4)*4+reg, col=lane&15
        size_t row = remap ? ((size_t)(m & 31) * T_ + (m >> 5)) : (size_t)m;
        C[row * (size_t)N + n] = acc[mi][ni][r] + bs;
      }
    }
  }
}

// ------------------------------ GRU scan ---------------------------------
// 32 blocks x 192 threads. Block ic owns channels i in [ic*16, ic*16+16).
// Wave w = gate (r,z,n): computes hg[b][gate*512 + ic*16 + i] for all 32 b via MFMA.
// w_hh slice (48 KB) lives in LDS (XOR-swizzled: 1KB row stride would be a
// 16-way bank conflict on ds_read_b128 otherwise). fp32 master h in LDS.
// Device-wide sync per step = flag-array barrier: per-block 64B-padded flag,
// relaxed agent stores/loads (MALL-resident), ONE release fence (wbl2) per
// block and ONE acquire fence (inv) per wave — no atomic RMW serialization,
// no per-poll buffer_inv.
__global__ __launch_bounds__(192) void gru_scan(
    const u16* __restrict__ whh_bf,   // [1536][512] bf16
    const float* __restrict__ xg,     // [(t*B+b)][1536] fp32 (b_ih already added)
    const float* __restrict__ bhh,    // [1536]
    const float* __restrict__ h0f,    // encoder_hidden fp32 [32][512]
    const u16* __restrict__ h0bf,     // [32][512] bf16
    u16* __restrict__ hs_bf,          // [(t*B+b)][512] bf16
    u32* __restrict__ bar)            // [32][16] u32 flags, 64B stride
{
  const int ic   = blockIdx.x;
  const int tid  = threadIdx.x;
  const int gate = tid >> 6;
  const int lane = tid & 63;
  const int q = lane >> 4, l16 = lane & 15;

  __shared__ u16  lW[3 * 16 * 512];   // 48 KB swizzled w_hh slice
  __shared__ float hgL[3][32][16];
  __shared__ float hSt[32][16];       // fp32 recurrent state for this i-chunk

  // ---- stage this block's w_hh rows into LDS, 16B granules, XOR-swizzled ----
  // 48 rows (gate*16 + r), each 512 u16 = 64 granules; granule c of row r goes
  // to byte (row*1024 + ((c ^ (r&15)) << 4)). Within a wave (same row, c=lane)
  // the write is a permutation of 64 granules -> conflict-free.
  for (int g16 = tid; g16 < 3072; g16 += 192) {
    int r48 = g16 >> 6;            // 0..47
    int c   = g16 & 63;            // granule within row
    int gg  = r48 >> 4;            // gate
    int rr  = r48 & 15;            // row within gate
    const uint4* src = (const uint4*)(whh_bf + (size_t)(gg * H_ + ic * 16 + rr) * H_) + c;
    *(uint4*)((char*)lW + r48 * 1024 + ((c ^ rr) << 4)) = *src;
  }

  for (int p = tid; p < 512; p += 192)
    hSt[p >> 4][p & 15] = h0f[(p >> 4) * H_ + ic * 16 + (p & 15)];

  // per-thread b_hh prefetch (constant across t) — static indices only
  float bh[3][3];
#pragma unroll
  for (int r = 0; r < 3; ++r) {
    int p = tid + r * 192;
    if (p < 512) {
      int g = ic * 16 + (p & 15);
      bh[r][0] = bhh[g]; bh[r][1] = bhh[H_ + g]; bh[r][2] = bhh[2 * H_ + g];
    }
  }
  __syncthreads();

  const int rowoff = (gate * 16 + l16) * 1024;   // LDS byte offset of this lane's W row

  for (int t = 0; t < T_; ++t) {
    // (A) prefetch this step's xg into registers — hides under MFMA phase
    float px[3][3];
#pragma unroll
    for (int r = 0; r < 3; ++r) {
      int p = tid + r * 192;
      if (p < 512) {
        const float* xrow = xg + ((size_t)t * B_ + (p >> 4)) * G3 + ic * 16 + (p & 15);
        px[r][0] = xrow[0]; px[r][1] = xrow[H_]; px[r][2] = xrow[2 * H_];
      }
    }

    // (B) MFMA: hg = h_prev @ w_hh^T for this wave's gate, 16 channels, 32 b
    const u16* hprev = (t == 0) ? h0bf : (hs_bf + (size_t)(t - 1) * (B_ * H_));
    f32x4 acc0 = {0.f, 0.f, 0.f, 0.f}, acc1 = {0.f, 0.f, 0.f, 0.f};
#pragma unroll
    for (int ks = 0; ks < 16; ++ks) {
      short8 bfr = *(const short8*)((const char*)lW + rowoff + ((((ks << 2) + q) ^ l16) << 4));
      short8 a0  = *(const short8*)(hprev + (size_t)l16 * H_ + ks * 32 + q * 8);
      short8 a1  = *(const short8*)(hprev + (size_t)(l16 + 16) * H_ + ks * 32 + q * 8);
      acc0 = __builtin_amdgcn_mfma_f32_16x16x32_bf16(a0, bfr, acc0, 0, 0, 0);
      acc1 = __builtin_amdgcn_mfma_f32_16x16x32_bf16(a1, bfr, acc1, 0, 0, 0);
    }
#pragma unroll
    for (int r = 0; r < 4; ++r) {
      hgL[gate][q * 4 + r][l16]      = acc0[r];
      hgL[gate][16 + q * 4 + r][l16] = acc1[r];
    }
    __syncthreads();

    // (D) combine — all inputs already in regs/LDS; only output store is global
#pragma unroll
    for (int r = 0; r < 3; ++r) {
      int p = tid + r * 192;
      if (p < 512) {
        int b = p >> 4, i = p & 15, g = ic * 16 + i;
        float hr = hgL[0][b][i] + bh[r][0];
        float hz = hgL[1][b][i] + bh[r][1];
        float hn = hgL[2][b][i] + bh[r][2];
        float rr = 1.f / (1.f + __expf(-(px[r][0] + hr)));
        float zz = 1.f / (1.f + __expf(-(px[r][1] + hz)));
        float xn2 = px[r][2] + rr * hn;
        float nn = 2.f / (1.f + __expf(-2.f * xn2)) - 1.f;   // tanh
        float hp = hSt[b][i];
        float hv = (1.f - zz) * nn + zz * hp;
        hSt[b][i] = hv;
        hs_bf[((size_t)t * B_ + b) * H_ + g] = f2bf(hv);
      }
    }

    // (E) flag-array device barrier
    if (t < T_ - 1) {
      __syncthreads();   // drains each wave's vmcnt -> all hs stores are in L2
      if (tid == 0) {
        __builtin_amdgcn_fence(__ATOMIC_RELEASE, "agent");   // wbl2: flush dirty L2 (all block's stores)
        __hip_atomic_store(bar + ic * 16, (u32)(t + 1),
                           __ATOMIC_RELAXED, __HIP_MEMORY_SCOPE_AGENT);
      }
      const u32 want = (u32)(t + 1);
      for (;;) {
        u32 v = __hip_atomic_load(bar + (lane & 31) * 16,
                                  __ATOMIC_RELAXED, __HIP_MEMORY_SCOPE_AGENT);
        if (__all((int)(v >= want))) break;
        __builtin_amdgcn_s_sleep(1);
      }
      __builtin_amdgcn_fence(__ATOMIC_ACQUIRE, "agent");     // inv: next hprev loads refetch
    }
  }
}

extern "C" void kernel_launch(void* const* d_in, const int* in_sizes, int n_in,
                              void* d_out, int out_size, void* d_ws, size_t ws_size,
                              hipStream_t stream) {
  const float* emb  = (const float*)d_in[0];   // [32000][512]
  const float* wih  = (const float*)d_in[1];   // [1536][512]
  const float* whh  = (const float*)d_in[2];   // [1536][512]
  const float* bih  = (const float*)d_in[3];   // [1536]
  const float* bhh  = (const float*)d_in[4];   // [1536]
  const float* bout = (const float*)d_in[5];   // [32000]
  const float* enc  = (const float*)d_in[6];   // [1][32][512]
  const int*   tgt  = (const int*)d_in[7];     // [32][128]
  float* out = (float*)d_out;

  // Buffers needed DURING the final (d_out-writing) GEMM live in ws:
  char* ws = (char*)d_ws;
  u16* emb_bf = (u16*)ws;                  // 32,768,000 B
  u16* hs_bf  = (u16*)(ws + 32768000);     //  4,194,304 B   (ws total 36.96 MB)

  // Everything else is dead before the final GEMM; carve from ws if roomy,
  // else from d_out (fully overwritten by the final GEMM afterwards).
  char* sc = (ws_size >= (size_t)70000000) ? (ws + 36962304) : (char*)d_out;
  u16*   wih_bf = (u16*)sc;                // 1,572,864
  u16*   whh_bf = (u16*)(sc + 1572864);    // 1,572,864
  u16*   x_bf   = (u16*)(sc + 3145728);    // 4,194,304
  float* xg     = (float*)(sc + 7340032);  // 25,165,824
  u16*   h0bf   = (u16*)(sc + 32505856);   //     32,768
  u32*   bar    = (u32*)(sc + 32538624);   //      2,048  (32 flags x 64B)

  cvt_bf16<<<dim3(2048), dim3(256), 0, stream>>>(emb, emb_bf, V_ * H_ / 4);
  cvt_bf16<<<dim3(256),  dim3(256), 0, stream>>>(wih, wih_bf, G3 * H_ / 4);
  cvt_bf16<<<dim3(256),  dim3(256), 0, stream>>>(whh, whh_bf, G3 * H_ / 4);
  cvt_bf16<<<dim3(16),   dim3(256), 0, stream>>>(enc, h0bf,  B_ * H_ / 4);
  gather_x<<<dim3(1024), dim3(256), 0, stream>>>(emb_bf, tgt, x_bf, bar);

  // xg = x @ w_ih^T + b_ih   [4096 x 1536], K=512
  gemm_bt<<<dim3(G3 / 128, 32), dim3(256), 0, stream>>>(
      x_bf, wih_bf, bih, xg, B_ * T_, G3, H_, 0);

  gru_scan<<<dim3(32), dim3(192), 0, stream>>>(whh_bf, xg, bhh, enc, h0bf, hs_bf, bar);

  // logits = hs @ emb^T + b_out  [4096 x 32000], K=512, remapped to [B,T,V]
  gemm_bt<<<dim3(V_ / 128, 32), dim3(256), 0, stream>>>(
      hs_bf, emb_bf, bout, out, B_ * T_, V_, H_, 1);
}